// Round 1
// baseline (23982.445 us; speedup 1.0000x reference)
//
#include <hip/hip_runtime.h>

#define N_HID 128

__device__ __forceinline__ float sigf(float x) { return 1.f / (1.f + __expf(-x)); }
// tanh(x) = 1 - 2/(exp(2x)+1)  (stable: +inf -> 1, -inf -> -1)
__device__ __forceinline__ float tanh_fast(float x) { return 1.f - 2.f / (__expf(2.f * x) + 1.f); }

// ---------------------------------------------------------------------------
// pad features [n,64] -> h [n,128] (zero upper half)
// one float4 per thread over n*32 float4s
__global__ __launch_bounds__(256) void pad_kernel(const float* __restrict__ feat,
                                                  float* __restrict__ h, int n) {
  int i = blockIdx.x * 256 + threadIdx.x;
  if (i >= n * 32) return;
  int node = i >> 5, c4 = i & 31;
  float4 v = make_float4(0.f, 0.f, 0.f, 0.f);
  if (c4 < 16) v = ((const float4*)feat)[(size_t)node * 16 + c4];
  ((float4*)h)[i] = v;
}

// ---------------------------------------------------------------------------
// m = h @ W^T + b   (W [128,128] row-major)
// block: 256 threads, 32 nodes. Full W transposed in LDS (64KB) + h tile (16KB)
// thread: cols {c, c+64}, 8 nodes -> 16 accumulators
__global__ __launch_bounds__(256) void lin_kernel(const float* __restrict__ h,
                                                  const float* __restrict__ W,
                                                  const float* __restrict__ b,
                                                  float* __restrict__ m, int n) {
  __shared__ float sW[N_HID][N_HID];               // sW[k][c] = W[c][k]
  __shared__ __align__(16) float sH[32][N_HID];
  const int tid = threadIdx.x;
  const int base = blockIdx.x * 32;

  // stage W transposed: each lane walks one row of W (L1-friendly), LDS writes conflict-free
  {
    int row = tid & 127;
    for (int k = tid >> 7; k < N_HID; k += 2)
      sW[k][row] = W[row * N_HID + k];
  }
  // stage h tile (coalesced float4)
  for (int idx = tid; idx < 32 * 32; idx += 256) {
    int node = idx >> 5, c4 = idx & 31;
    int gn = base + node;
    if (gn >= n) gn = n - 1;
    ((float4*)&sH[node][0])[c4] = ((const float4*)h)[(size_t)gn * 32 + c4];
  }
  __syncthreads();

  const int c = tid & 63;
  const int slot = tid >> 6;  // 0..3 -> nodes slot*8 .. slot*8+7
  float acc0[8], acc1[8];
#pragma unroll
  for (int i = 0; i < 8; i++) { acc0[i] = 0.f; acc1[i] = 0.f; }

  for (int k = 0; k < N_HID; k += 4) {
    float w0[4], w1[4];
#pragma unroll
    for (int j = 0; j < 4; j++) { w0[j] = sW[k + j][c]; w1[j] = sW[k + j][c + 64]; }
#pragma unroll
    for (int i = 0; i < 8; i++) {
      float4 hv = *(const float4*)&sH[slot * 8 + i][k];
      acc0[i] = fmaf(hv.x, w0[0], fmaf(hv.y, w0[1], fmaf(hv.z, w0[2], fmaf(hv.w, w0[3], acc0[i]))));
      acc1[i] = fmaf(hv.x, w1[0], fmaf(hv.y, w1[1], fmaf(hv.z, w1[2], fmaf(hv.w, w1[3], acc1[i]))));
    }
  }
  float b0 = b[c], b1 = b[c + 64];
#pragma unroll
  for (int i = 0; i < 8; i++) {
    int node = base + slot * 8 + i;
    if (node < n) {
      m[(size_t)node * N_HID + c] = acc0[i] + b0;
      m[(size_t)node * N_HID + c + 64] = acc1[i] + b1;
    }
  }
}

// ---------------------------------------------------------------------------
// a[dst] += m[src]  (atomic scatter-add), one float4 of the row per thread
__global__ __launch_bounds__(256) void scatter_kernel(const float* __restrict__ m,
                                                      const int* __restrict__ src,
                                                      const int* __restrict__ dst,
                                                      float* __restrict__ a, int n_edges) {
  int i = blockIdx.x * 256 + threadIdx.x;
  int e = i >> 5;
  if (e >= n_edges) return;
  int c4 = i & 31;
  int s = src[e], d = dst[e];
  float4 v = ((const float4*)m)[(size_t)s * 32 + c4];
  float* ap = a + (size_t)d * N_HID + c4 * 4;
  atomicAdd(ap + 0, v.x);
  atomicAdd(ap + 1, v.y);
  atomicAdd(ap + 2, v.z);
  atomicAdd(ap + 3, v.w);
}

// ---------------------------------------------------------------------------
// h = GRUCell(a, h): gi = a@w_ih^T + b_ih ; gh = h@w_hh^T + b_hh
// gates (r,z,n): r=sig(i_r+h_r) z=sig(i_z+h_z) n=tanh(i_n + r*h_n) h'=(1-z)n+z h
// block: 256 threads, 32 nodes. a/h tiles in LDS; weights k-chunked transposed in LDS.
// thread: col c (0..127), 16 nodes (slot in {0,1}), 6 accumulators per node.
#define KC 8
__global__ __launch_bounds__(256) void gru_kernel(const float* __restrict__ a,
                                                  float* __restrict__ h,
                                                  const float* __restrict__ w_ih,
                                                  const float* __restrict__ w_hh,
                                                  const float* __restrict__ b_ih,
                                                  const float* __restrict__ b_hh, int n) {
  __shared__ __align__(16) float sA[32][N_HID];
  __shared__ __align__(16) float sH[32][N_HID];
  __shared__ float sWih[KC][3 * N_HID];  // sWih[k][gc] = w_ih[gc][kc+k]
  __shared__ float sWhh[KC][3 * N_HID];
  const int tid = threadIdx.x;
  const int base = blockIdx.x * 32;

  for (int idx = tid; idx < 32 * 32; idx += 256) {
    int node = idx >> 5, c4 = idx & 31;
    int gn = base + node;
    if (gn >= n) gn = n - 1;
    ((float4*)&sA[node][0])[c4] = ((const float4*)a)[(size_t)gn * 32 + c4];
    ((float4*)&sH[node][0])[c4] = ((const float4*)h)[(size_t)gn * 32 + c4];
  }

  const int c = tid & 127;
  const int slot = tid >> 7;  // 0..1 -> nodes slot*16 .. slot*16+15
  float aR[16], aZ[16], aN[16], hR[16], hZ[16], hN[16];
#pragma unroll
  for (int i = 0; i < 16; i++) { aR[i] = aZ[i] = aN[i] = hR[i] = hZ[i] = hN[i] = 0.f; }

  for (int kc = 0; kc < N_HID; kc += KC) {
    __syncthreads();  // protects tile staging (first iter) / previous chunk use
    for (int k = 0; k < KC; k++) {
      for (int gc = tid; gc < 3 * N_HID; gc += 256) {
        sWih[k][gc] = w_ih[gc * N_HID + kc + k];
        sWhh[k][gc] = w_hh[gc * N_HID + kc + k];
      }
    }
    __syncthreads();
#pragma unroll
    for (int k4 = 0; k4 < KC; k4 += 4) {
      float wi0[4], wi1[4], wi2[4], wh0[4], wh1[4], wh2[4];
#pragma unroll
      for (int j = 0; j < 4; j++) {
        wi0[j] = sWih[k4 + j][c];
        wi1[j] = sWih[k4 + j][128 + c];
        wi2[j] = sWih[k4 + j][256 + c];
        wh0[j] = sWhh[k4 + j][c];
        wh1[j] = sWhh[k4 + j][128 + c];
        wh2[j] = sWhh[k4 + j][256 + c];
      }
#pragma unroll
      for (int i = 0; i < 16; i++) {
        int node = slot * 16 + i;
        float4 av = *(const float4*)&sA[node][kc + k4];
        float4 hv = *(const float4*)&sH[node][kc + k4];
        aR[i] = fmaf(av.x, wi0[0], fmaf(av.y, wi0[1], fmaf(av.z, wi0[2], fmaf(av.w, wi0[3], aR[i]))));
        aZ[i] = fmaf(av.x, wi1[0], fmaf(av.y, wi1[1], fmaf(av.z, wi1[2], fmaf(av.w, wi1[3], aZ[i]))));
        aN[i] = fmaf(av.x, wi2[0], fmaf(av.y, wi2[1], fmaf(av.z, wi2[2], fmaf(av.w, wi2[3], aN[i]))));
        hR[i] = fmaf(hv.x, wh0[0], fmaf(hv.y, wh0[1], fmaf(hv.z, wh0[2], fmaf(hv.w, wh0[3], hR[i]))));
        hZ[i] = fmaf(hv.x, wh1[0], fmaf(hv.y, wh1[1], fmaf(hv.z, wh1[2], fmaf(hv.w, wh1[3], hZ[i]))));
        hN[i] = fmaf(hv.x, wh2[0], fmaf(hv.y, wh2[1], fmaf(hv.z, wh2[2], fmaf(hv.w, wh2[3], hN[i]))));
      }
    }
  }

  float biR = b_ih[c], biZ = b_ih[128 + c], biN = b_ih[256 + c];
  float bhR = b_hh[c], bhZ = b_hh[128 + c], bhN = b_hh[256 + c];
#pragma unroll
  for (int i = 0; i < 16; i++) {
    int node = slot * 16 + i;
    int gn = base + node;
    if (gn < n) {
      float r = sigf(aR[i] + biR + hR[i] + bhR);
      float z = sigf(aZ[i] + biZ + hZ[i] + bhZ);
      float nn = tanh_fast(aN[i] + biN + r * (hN[i] + bhN));
      float hv = sH[node][c];
      h[(size_t)gn * N_HID + c] = (1.f - z) * nn + z * hv;
    }
  }
}

// ---------------------------------------------------------------------------
// out = h @ fc_w^T + fc_b  -> [n, 2]; one wave per node, shuffle reduce
__global__ __launch_bounds__(256) void head_kernel(const float* __restrict__ h,
                                                   const float* __restrict__ fc_w,
                                                   const float* __restrict__ fc_b,
                                                   float* __restrict__ out, int n) {
  int wave = (blockIdx.x * 256 + threadIdx.x) >> 6;
  int lane = threadIdx.x & 63;
  if (wave >= n) return;
  float2 hv = ((const float2*)h)[(size_t)wave * 64 + lane];
  float2 w0 = ((const float2*)fc_w)[lane];
  float2 w1 = ((const float2*)fc_w)[64 + lane];
  float p0 = hv.x * w0.x + hv.y * w0.y;
  float p1 = hv.x * w1.x + hv.y * w1.y;
#pragma unroll
  for (int off = 32; off > 0; off >>= 1) {
    p0 += __shfl_down(p0, off, 64);
    p1 += __shfl_down(p1, off, 64);
  }
  if (lane == 0) {
    out[(size_t)wave * 2 + 0] = p0 + fc_b[0];
    out[(size_t)wave * 2 + 1] = p1 + fc_b[1];
  }
}

// ---------------------------------------------------------------------------
extern "C" void kernel_launch(void* const* d_in, const int* in_sizes, int n_in,
                              void* d_out, int out_size, void* d_ws, size_t ws_size,
                              hipStream_t stream) {
  const float* feat = (const float*)d_in[0];
  const int* src = (const int*)d_in[1];
  const int* dst = (const int*)d_in[2];
  const int N = in_sizes[0] / 64;
  const int E = in_sizes[1];

  const float* Wl[2]  = {(const float*)d_in[3], (const float*)d_in[9]};
  const float* bl[2]  = {(const float*)d_in[4], (const float*)d_in[10]};
  const float* wih[2] = {(const float*)d_in[5], (const float*)d_in[11]};
  const float* whh[2] = {(const float*)d_in[6], (const float*)d_in[12]};
  const float* bih[2] = {(const float*)d_in[7], (const float*)d_in[13]};
  const float* bhh[2] = {(const float*)d_in[8], (const float*)d_in[14]};
  const float* fcw = (const float*)d_in[15];
  const float* fcb = (const float*)d_in[16];

  float* h = (float*)d_ws;
  float* m = h + (size_t)N * N_HID;
  float* aa = m + (size_t)N * N_HID;
  size_t hbytes = (size_t)N * N_HID * sizeof(float);

  pad_kernel<<<(N * 32 + 255) / 256, 256, 0, stream>>>(feat, h, N);

  int nblk = (N + 31) / 32;
  for (int layer = 0; layer < 2; layer++) {
    for (int step = 0; step < 5; step++) {
      lin_kernel<<<nblk, 256, 0, stream>>>(h, Wl[layer], bl[layer], m, N);
      hipMemsetAsync(aa, 0, hbytes, stream);
      scatter_kernel<<<(E * 32 + 255) / 256, 256, 0, stream>>>(m, src, dst, aa, E);
      gru_kernel<<<nblk, 256, 0, stream>>>(aa, h, wih[layer], whh[layer], bih[layer], bhh[layer], N);
    }
  }

  head_kernel<<<(N + 3) / 4, 256, 0, stream>>>(h, fcw, fcb, (float*)d_out, N);
}

// Round 2
// 6896.461 us; speedup vs baseline: 3.4775x; 3.4775x over previous
//
#include <hip/hip_runtime.h>

#define N_HID 128

__device__ __forceinline__ float sigf(float x) { return 1.f / (1.f + __expf(-x)); }
__device__ __forceinline__ float tanh_fast(float x) { return 1.f - 2.f / (__expf(2.f * x) + 1.f); }

// ---------------------------------------------------------------------------
// generic naive transpose: src [R][C] row-major -> dst [C][R] row-major
__global__ __launch_bounds__(256) void transpose_kernel(const float* __restrict__ src,
                                                        float* __restrict__ dst, int R, int C) {
  int i = blockIdx.x * 256 + threadIdx.x;
  if (i >= R * C) return;
  int r = i / C, c = i % C;
  dst[c * R + r] = src[i];
}

// pad features [n,64] -> h [n,128]
__global__ __launch_bounds__(256) void pad_kernel(const float* __restrict__ feat,
                                                  float* __restrict__ h, int n) {
  int i = blockIdx.x * 256 + threadIdx.x;
  if (i >= n * 32) return;
  int node = i >> 5, c4 = i & 31;
  float4 v = make_float4(0.f, 0.f, 0.f, 0.f);
  if (c4 < 16) v = ((const float4*)feat)[(size_t)node * 16 + c4];
  ((float4*)h)[i] = v;
}

// ---------------------------------------------------------------------------
// CSR build
__global__ __launch_bounds__(256) void hist_kernel(const int* __restrict__ dst,
                                                   int* __restrict__ deg, int E) {
  int e = blockIdx.x * 256 + threadIdx.x;
  if (e < E) atomicAdd(&deg[dst[e]], 1);
}

// per-block exclusive scan over 4096 elems (256 thr x 16), writes block total
__global__ __launch_bounds__(256) void scan1_kernel(const int* __restrict__ deg,
                                                    int* __restrict__ out,
                                                    int* __restrict__ bsums, int n) {
  __shared__ int s[256];
  int t = threadIdx.x;
  int base = blockIdx.x * 4096 + t * 16;
  int v[16];
  int local = 0;
#pragma unroll
  for (int i = 0; i < 16; i++) {
    int x = (base + i < n) ? deg[base + i] : 0;
    v[i] = local;
    local += x;
  }
  s[t] = local;
  __syncthreads();
  for (int off = 1; off < 256; off <<= 1) {
    int add = (t >= off) ? s[t - off] : 0;
    __syncthreads();
    s[t] += add;
    __syncthreads();
  }
  int texcl = s[t] - local;  // exclusive prefix of this thread's chunk
#pragma unroll
  for (int i = 0; i < 16; i++)
    if (base + i < n) out[base + i] = texcl + v[i];
  if (t == 255) bsums[blockIdx.x] = s[255];
}

// exclusive scan of block sums (nb <= 256), single block
__global__ __launch_bounds__(256) void scan_tops_kernel(int* __restrict__ bsums, int nb) {
  __shared__ int s[256];
  int t = threadIdx.x;
  int orig = (t < nb) ? bsums[t] : 0;
  s[t] = orig;
  __syncthreads();
  for (int off = 1; off < 256; off <<= 1) {
    int add = (t >= off) ? s[t - off] : 0;
    __syncthreads();
    s[t] += add;
    __syncthreads();
  }
  if (t < nb) bsums[t] = s[t] - orig;
}

__global__ __launch_bounds__(256) void scan_add_kernel(int* __restrict__ rowptr,
                                                       const int* __restrict__ bsums,
                                                       int n, int E) {
  int i = blockIdx.x * 256 + threadIdx.x;
  if (i < n) rowptr[i] += bsums[i / 4096];
  if (i == n) rowptr[n] = E;
}

__global__ __launch_bounds__(256) void bucket_kernel(const int* __restrict__ src,
                                                     const int* __restrict__ dst,
                                                     const int* __restrict__ rowptr,
                                                     int* __restrict__ cursor,
                                                     int* __restrict__ csr_src, int E) {
  int e = blockIdx.x * 256 + threadIdx.x;
  if (e >= E) return;
  int d = dst[e];
  int p = atomicAdd(&cursor[d], 1);
  csr_src[rowptr[d] + p] = src[e];
}

// ---------------------------------------------------------------------------
// a[d] = sum over incoming edges of m[src]; 32 lanes (float4 each) per node
__global__ __launch_bounds__(256) void gather_kernel(const float* __restrict__ m,
                                                     const int* __restrict__ rowptr,
                                                     const int* __restrict__ csr_src,
                                                     float* __restrict__ a, int n) {
  int tid = threadIdx.x;
  int node = blockIdx.x * 8 + (tid >> 5);
  if (node >= n) return;
  int c4 = tid & 31;
  int beg = rowptr[node], end = rowptr[node + 1];
  float4 acc = make_float4(0.f, 0.f, 0.f, 0.f);
  int j = beg;
  for (; j + 1 < end; j += 2) {
    int s0 = csr_src[j], s1 = csr_src[j + 1];
    float4 v0 = ((const float4*)m)[(size_t)s0 * 32 + c4];
    float4 v1 = ((const float4*)m)[(size_t)s1 * 32 + c4];
    acc.x += v0.x + v1.x; acc.y += v0.y + v1.y;
    acc.z += v0.z + v1.z; acc.w += v0.w + v1.w;
  }
  if (j < end) {
    int s0 = csr_src[j];
    float4 v0 = ((const float4*)m)[(size_t)s0 * 32 + c4];
    acc.x += v0.x; acc.y += v0.y; acc.z += v0.z; acc.w += v0.w;
  }
  ((float4*)a)[(size_t)node * 32 + c4] = acc;
}

// ---------------------------------------------------------------------------
// m = h @ W^T + b, weights pre-transposed: WT[k][c] = W[c][k]
// block: 256 thr, 32 nodes; thread: col c (0..127), 16 nodes
__global__ __launch_bounds__(256) void lin_kernel(const float* __restrict__ h,
                                                  const float* __restrict__ WT,
                                                  const float* __restrict__ b,
                                                  float* __restrict__ m, int n) {
  __shared__ __align__(16) float sH[32][N_HID];
  const int tid = threadIdx.x;
  const int base = blockIdx.x * 32;
  for (int idx = tid; idx < 32 * 32; idx += 256) {
    int node = idx >> 5, c4 = idx & 31;
    int gn = base + node;
    if (gn >= n) gn = n - 1;
    ((float4*)&sH[node][0])[c4] = ((const float4*)h)[(size_t)gn * 32 + c4];
  }
  __syncthreads();

  const int c = tid & 127;
  const int slot = tid >> 7;
  float acc[16];
#pragma unroll
  for (int i = 0; i < 16; i++) acc[i] = 0.f;

#pragma unroll 2
  for (int k = 0; k < N_HID; k += 4) {
    float w[4];
#pragma unroll
    for (int j = 0; j < 4; j++) w[j] = WT[(k + j) * N_HID + c];
#pragma unroll
    for (int i = 0; i < 16; i++) {
      float4 hv = *(const float4*)&sH[slot * 16 + i][k];
      acc[i] = fmaf(hv.x, w[0], fmaf(hv.y, w[1], fmaf(hv.z, w[2], fmaf(hv.w, w[3], acc[i]))));
    }
  }
  float bb = b[c];
#pragma unroll
  for (int i = 0; i < 16; i++) {
    int node = base + slot * 16 + i;
    if (node < n) m[(size_t)node * N_HID + c] = acc[i] + bb;
  }
}

// ---------------------------------------------------------------------------
// GRU: weights pre-transposed [128][384]: wT[k][gate*128+c]
// block: 256 thr, 32 nodes; thread: col c, 16 nodes, 4 accumulators/node
__global__ __launch_bounds__(256, 4) void gru_kernel(const float* __restrict__ a,
                                                     float* __restrict__ h,
                                                     const float* __restrict__ wihT,
                                                     const float* __restrict__ whhT,
                                                     const float* __restrict__ b_ih,
                                                     const float* __restrict__ b_hh, int n) {
  __shared__ __align__(16) float sA[32][N_HID];
  __shared__ __align__(16) float sH[32][N_HID];
  const int tid = threadIdx.x;
  const int base = blockIdx.x * 32;

  for (int idx = tid; idx < 32 * 32; idx += 256) {
    int node = idx >> 5, c4 = idx & 31;
    int gn = base + node;
    if (gn >= n) gn = n - 1;
    ((float4*)&sA[node][0])[c4] = ((const float4*)a)[(size_t)gn * 32 + c4];
    ((float4*)&sH[node][0])[c4] = ((const float4*)h)[(size_t)gn * 32 + c4];
  }
  __syncthreads();

  const int c = tid & 127;
  const int slot = tid >> 7;
  // accR = i_r + h_r ; accZ = i_z + h_z ; accIN = i_n ; accHN = h_n
  float accR[16], accZ[16], accIN[16], accHN[16];
#pragma unroll
  for (int i = 0; i < 16; i++) { accR[i] = accZ[i] = accIN[i] = accHN[i] = 0.f; }

#pragma unroll 2
  for (int k4 = 0; k4 < N_HID; k4 += 4) {
    float wi0[4], wi1[4], wi2[4], wh0[4], wh1[4], wh2[4];
#pragma unroll
    for (int j = 0; j < 4; j++) {
      const float* wi = wihT + (size_t)(k4 + j) * 384;
      const float* wh = whhT + (size_t)(k4 + j) * 384;
      wi0[j] = wi[c]; wi1[j] = wi[128 + c]; wi2[j] = wi[256 + c];
      wh0[j] = wh[c]; wh1[j] = wh[128 + c]; wh2[j] = wh[256 + c];
    }
#pragma unroll
    for (int i = 0; i < 16; i++) {
      int node = slot * 16 + i;
      float4 av = *(const float4*)&sA[node][k4];
      float4 hv = *(const float4*)&sH[node][k4];
      accR[i] = fmaf(av.x, wi0[0], fmaf(av.y, wi0[1], fmaf(av.z, wi0[2], fmaf(av.w, wi0[3], accR[i]))));
      accR[i] = fmaf(hv.x, wh0[0], fmaf(hv.y, wh0[1], fmaf(hv.z, wh0[2], fmaf(hv.w, wh0[3], accR[i]))));
      accZ[i] = fmaf(av.x, wi1[0], fmaf(av.y, wi1[1], fmaf(av.z, wi1[2], fmaf(av.w, wi1[3], accZ[i]))));
      accZ[i] = fmaf(hv.x, wh1[0], fmaf(hv.y, wh1[1], fmaf(hv.z, wh1[2], fmaf(hv.w, wh1[3], accZ[i]))));
      accIN[i] = fmaf(av.x, wi2[0], fmaf(av.y, wi2[1], fmaf(av.z, wi2[2], fmaf(av.w, wi2[3], accIN[i]))));
      accHN[i] = fmaf(hv.x, wh2[0], fmaf(hv.y, wh2[1], fmaf(hv.z, wh2[2], fmaf(hv.w, wh2[3], accHN[i]))));
    }
  }

  float biR = b_ih[c], biZ = b_ih[128 + c], biN = b_ih[256 + c];
  float bhR = b_hh[c], bhZ = b_hh[128 + c], bhN = b_hh[256 + c];
#pragma unroll
  for (int i = 0; i < 16; i++) {
    int node = slot * 16 + i;
    int gn = base + node;
    if (gn < n) {
      float r = sigf(accR[i] + biR + bhR);
      float z = sigf(accZ[i] + biZ + bhZ);
      float nn = tanh_fast(accIN[i] + biN + r * (accHN[i] + bhN));
      float hv = sH[node][c];
      h[(size_t)gn * N_HID + c] = (1.f - z) * nn + z * hv;
    }
  }
}

// ---------------------------------------------------------------------------
__global__ __launch_bounds__(256) void head_kernel(const float* __restrict__ h,
                                                   const float* __restrict__ fc_w,
                                                   const float* __restrict__ fc_b,
                                                   float* __restrict__ out, int n) {
  int wave = (blockIdx.x * 256 + threadIdx.x) >> 6;
  int lane = threadIdx.x & 63;
  if (wave >= n) return;
  float2 hv = ((const float2*)h)[(size_t)wave * 64 + lane];
  float2 w0 = ((const float2*)fc_w)[lane];
  float2 w1 = ((const float2*)fc_w)[64 + lane];
  float p0 = hv.x * w0.x + hv.y * w0.y;
  float p1 = hv.x * w1.x + hv.y * w1.y;
#pragma unroll
  for (int off = 32; off > 0; off >>= 1) {
    p0 += __shfl_down(p0, off, 64);
    p1 += __shfl_down(p1, off, 64);
  }
  if (lane == 0) {
    out[(size_t)wave * 2 + 0] = p0 + fc_b[0];
    out[(size_t)wave * 2 + 1] = p1 + fc_b[1];
  }
}

// ---------------------------------------------------------------------------
extern "C" void kernel_launch(void* const* d_in, const int* in_sizes, int n_in,
                              void* d_out, int out_size, void* d_ws, size_t ws_size,
                              hipStream_t stream) {
  const float* feat = (const float*)d_in[0];
  const int* src = (const int*)d_in[1];
  const int* dst = (const int*)d_in[2];
  const int N = in_sizes[0] / 64;
  const int E = in_sizes[1];

  const float* Wl[2]  = {(const float*)d_in[3], (const float*)d_in[9]};
  const float* bl[2]  = {(const float*)d_in[4], (const float*)d_in[10]};
  const float* wih[2] = {(const float*)d_in[5], (const float*)d_in[11]};
  const float* whh[2] = {(const float*)d_in[6], (const float*)d_in[12]};
  const float* bih[2] = {(const float*)d_in[7], (const float*)d_in[13]};
  const float* bhh[2] = {(const float*)d_in[8], (const float*)d_in[14]};
  const float* fcw = (const float*)d_in[15];
  const float* fcb = (const float*)d_in[16];

  float* h = (float*)d_ws;
  float* m = h + (size_t)N * N_HID;
  float* aa = m + (size_t)N * N_HID;
  int* rowptr = (int*)(aa + (size_t)N * N_HID);
  int* deg = rowptr + (N + 1);           // reused as cursor for bucket
  int* csr_src = deg + N;
  int* bsums = csr_src + E;
  float* WT[2];
  WT[0] = (float*)(bsums + 256);
  WT[1] = WT[0] + 128 * 128;
  float* wihT[2] = {WT[1] + 128 * 128, WT[1] + 128 * 128 + 384 * 128 * 2};
  float* whhT[2] = {wihT[0] + 384 * 128, wihT[1] + 384 * 128};

  // --- one-time per launch: weight transposes + pad + CSR build ---
  for (int l = 0; l < 2; l++) {
    transpose_kernel<<<(128 * 128 + 255) / 256, 256, 0, stream>>>(Wl[l], WT[l], 128, 128);
    transpose_kernel<<<(384 * 128 + 255) / 256, 256, 0, stream>>>(wih[l], wihT[l], 384, 128);
    transpose_kernel<<<(384 * 128 + 255) / 256, 256, 0, stream>>>(whh[l], whhT[l], 384, 128);
  }
  pad_kernel<<<(N * 32 + 255) / 256, 256, 0, stream>>>(feat, h, N);

  int nb = (N + 4095) / 4096;
  hipMemsetAsync(deg, 0, (size_t)N * sizeof(int), stream);
  hist_kernel<<<(E + 255) / 256, 256, 0, stream>>>(dst, deg, E);
  scan1_kernel<<<nb, 256, 0, stream>>>(deg, rowptr, bsums, N);
  scan_tops_kernel<<<1, 256, 0, stream>>>(bsums, nb);
  scan_add_kernel<<<(N + 256) / 256, 256, 0, stream>>>(rowptr, bsums, N, E);
  hipMemsetAsync(deg, 0, (size_t)N * sizeof(int), stream);
  bucket_kernel<<<(E + 255) / 256, 256, 0, stream>>>(src, dst, rowptr, deg, csr_src, E);

  // --- main loop ---
  int nblk = (N + 31) / 32;
  for (int layer = 0; layer < 2; layer++) {
    for (int step = 0; step < 5; step++) {
      lin_kernel<<<nblk, 256, 0, stream>>>(h, WT[layer], bl[layer], m, N);
      gather_kernel<<<(N + 7) / 8, 256, 0, stream>>>(m, rowptr, csr_src, aa, N);
      gru_kernel<<<nblk, 256, 0, stream>>>(aa, h, wihT[layer], whhT[layer], bih[layer], bhh[layer], N);
    }
  }

  head_kernel<<<(N + 3) / 4, 256, 0, stream>>>(h, fcw, fcb, (float*)d_out, N);
}

// Round 5
// 1478.707 us; speedup vs baseline: 16.2185x; 4.6638x over previous
//
#include <hip/hip_runtime.h>

#define N_HID 128
typedef unsigned short u16;
typedef unsigned int u32;
typedef __attribute__((ext_vector_type(8))) short bfrag;   // 8 bf16 = 4 VGPR
typedef __attribute__((ext_vector_type(4))) float facc;    // 4 f32 acc

__device__ __forceinline__ float sigf(float x) { return 1.f / (1.f + __expf(-x)); }
__device__ __forceinline__ float tanh_fast(float x) { return 1.f - 2.f / (__expf(2.f * x) + 1.f); }
__device__ __forceinline__ u16 f2bf(float f) {
  u32 u = __float_as_uint(f);
  u += 0x7fffu + ((u >> 16) & 1u);
  return (u16)(u >> 16);
}
__device__ __forceinline__ float bf2f(u16 b) { return __uint_as_float(((u32)b) << 16); }

// ---------------------------------------------------------------------------
// pack W [128,128] (row-major W[c][k]) into B-frag layout bf16:
// PB[((kt*8 + ct)*64 + l)*8 + e] = W[col=ct*16+(l&15)][k=kt*32+(l>>4)*8+e]
__global__ __launch_bounds__(256) void pack_lin_kernel(const float* __restrict__ W,
                                                       u16* __restrict__ PB) {
  int i = blockIdx.x * 256 + threadIdx.x;  // 4*8*64*8 = 16384
  if (i >= 16384) return;
  int e = i & 7, l = (i >> 3) & 63, ct = (i >> 9) & 7, kt = i >> 12;
  int col = ct * 16 + (l & 15);
  int k = kt * 32 + ((l >> 4) << 3) + e;
  PB[i] = f2bf(W[col * 128 + k]);
}

// pack GRU weights. Packed col-tiles pct 0..31: w=pct>>3, t=pct&7,
// kind=t>>1 (0=r,1=z,2=i_n,3=h_n), sub=t&1, ch=w*32+sub*16+(l&15).
// K axis = [a(0..127) | h(128..255)], k = kt*32+(l>>4)*8+e.
__global__ __launch_bounds__(256) void pack_gru_kernel(const float* __restrict__ wih,
                                                       const float* __restrict__ whh,
                                                       u16* __restrict__ GB) {
  int i = blockIdx.x * 256 + threadIdx.x;  // 8*32*64*8 = 131072
  if (i >= 131072) return;
  int e = i & 7, l = (i >> 3) & 63, pct = (i >> 9) & 31, kt = i >> 14;
  int w = pct >> 3, t = pct & 7, kind = t >> 1, sub = t & 1;
  int ch = w * 32 + sub * 16 + (l & 15);
  int k = kt * 32 + ((l >> 4) << 3) + e;
  float v = 0.f;
  if (kind == 0) v = (k < 128) ? wih[ch * 128 + k] : whh[ch * 128 + k - 128];
  else if (kind == 1) v = (k < 128) ? wih[(128 + ch) * 128 + k] : whh[(128 + ch) * 128 + k - 128];
  else if (kind == 2) v = (k < 128) ? wih[(256 + ch) * 128 + k] : 0.f;
  else v = (k >= 128) ? whh[(256 + ch) * 128 + k - 128] : 0.f;
  GB[i] = f2bf(v);
}

// ---------------------------------------------------------------------------
// pad features [n,64] -> h f32 [n,128] and hbf bf16 [n,128]
__global__ __launch_bounds__(256) void pad2_kernel(const float* __restrict__ feat,
                                                   float* __restrict__ h,
                                                   u16* __restrict__ hbf, int n) {
  int i = blockIdx.x * 256 + threadIdx.x;
  if (i >= n * 32) return;
  int node = i >> 5, c4 = i & 31;
  float4 v = make_float4(0.f, 0.f, 0.f, 0.f);
  if (c4 < 16) v = ((const float4*)feat)[(size_t)node * 16 + c4];
  ((float4*)h)[i] = v;
  u32 p0 = (u32)f2bf(v.x) | ((u32)f2bf(v.y) << 16);
  u32 p1 = (u32)f2bf(v.z) | ((u32)f2bf(v.w) << 16);
  ((uint2*)hbf)[i] = make_uint2(p0, p1);
}

// ---------------------------------------------------------------------------
// CSR build
__global__ __launch_bounds__(256) void hist_kernel(const int* __restrict__ dst,
                                                   int* __restrict__ deg, int E) {
  int e = blockIdx.x * 256 + threadIdx.x;
  if (e < E) atomicAdd(&deg[dst[e]], 1);
}

__global__ __launch_bounds__(256) void scan1_kernel(const int* __restrict__ deg,
                                                    int* __restrict__ out,
                                                    int* __restrict__ bsums, int n) {
  __shared__ int s[256];
  int t = threadIdx.x;
  int base = blockIdx.x * 4096 + t * 16;
  int v[16];
  int local = 0;
#pragma unroll
  for (int i = 0; i < 16; i++) {
    int x = (base + i < n) ? deg[base + i] : 0;
    v[i] = local;
    local += x;
  }
  s[t] = local;
  __syncthreads();
  for (int off = 1; off < 256; off <<= 1) {
    int add = (t >= off) ? s[t - off] : 0;
    __syncthreads();
    s[t] += add;
    __syncthreads();
  }
  int texcl = s[t] - local;
#pragma unroll
  for (int i = 0; i < 16; i++)
    if (base + i < n) out[base + i] = texcl + v[i];
  if (t == 255) bsums[blockIdx.x] = s[255];
}

__global__ __launch_bounds__(256) void scan_tops_kernel(int* __restrict__ bsums, int nb) {
  __shared__ int s[256];
  int t = threadIdx.x;
  int orig = (t < nb) ? bsums[t] : 0;
  s[t] = orig;
  __syncthreads();
  for (int off = 1; off < 256; off <<= 1) {
    int add = (t >= off) ? s[t - off] : 0;
    __syncthreads();
    s[t] += add;
    __syncthreads();
  }
  if (t < nb) bsums[t] = s[t] - orig;
}

__global__ __launch_bounds__(256) void scan_add_kernel(int* __restrict__ rowptr,
                                                       const int* __restrict__ bsums,
                                                       int n, int E) {
  int i = blockIdx.x * 256 + threadIdx.x;
  if (i < n) rowptr[i] += bsums[i / 4096];
  if (i == n) rowptr[n] = E;
}

__global__ __launch_bounds__(256) void bucket_kernel(const int* __restrict__ src,
                                                     const int* __restrict__ dst,
                                                     const int* __restrict__ rowptr,
                                                     int* __restrict__ cursor,
                                                     int* __restrict__ csr_src, int E) {
  int e = blockIdx.x * 256 + threadIdx.x;
  if (e >= E) return;
  int d = dst[e];
  int p = atomicAdd(&cursor[d], 1);
  csr_src[rowptr[d] + p] = src[e];
}

// ---------------------------------------------------------------------------
// a_bf[d] = bf16( sum_{incoming} f32(m_bf[src]) ); 32 lanes x 4 channels per node
__global__ __launch_bounds__(256) void gather_kernel(const u16* __restrict__ mbf,
                                                     const int* __restrict__ rowptr,
                                                     const int* __restrict__ csr_src,
                                                     u16* __restrict__ abf, int n) {
  int tid = threadIdx.x;
  int node = blockIdx.x * 8 + (tid >> 5);
  if (node >= n) return;
  int c = tid & 31;  // 4 bf16 channels: c*4 .. c*4+3
  int beg = rowptr[node], end = rowptr[node + 1];
  float a0 = 0.f, a1 = 0.f, a2 = 0.f, a3 = 0.f;
  for (int j = beg; j < end; j++) {
    int s = csr_src[j];
    uint2 mv = ((const uint2*)mbf)[(size_t)s * 32 + c];
    a0 += bf2f((u16)(mv.x & 0xffff));
    a1 += bf2f((u16)(mv.x >> 16));
    a2 += bf2f((u16)(mv.y & 0xffff));
    a3 += bf2f((u16)(mv.y >> 16));
  }
  u32 p0 = (u32)f2bf(a0) | ((u32)f2bf(a1) << 16);
  u32 p1 = (u32)f2bf(a2) | ((u32)f2bf(a3) << 16);
  ((uint2*)abf)[(size_t)node * 32 + c] = make_uint2(p0, p1);
}

// ---------------------------------------------------------------------------
// m_bf = bf16( hbf @ W^T + b ) via MFMA. Block: 256 thr = 4 waves, 32 nodes.
// Wave w: cols w*32..w*32+31 (2 col-tiles), 2 row-tiles, K=128 (4 k-tiles).
__global__ __launch_bounds__(256) void lin_mfma_kernel(const u16* __restrict__ hbf,
                                                       const u16* __restrict__ PB,
                                                       const float* __restrict__ b,
                                                       u16* __restrict__ mbf, int n) {
  __shared__ __align__(16) u16 sX[32 * 128];  // 8KB, XOR-swizzled
  const int tid = threadIdx.x;
  const int base = blockIdx.x * 32;
  // stage: 512 x 16B chunks
  for (int it = 0; it < 2; it++) {
    int cid = tid + 256 * it;
    int node = cid >> 4, c16 = cid & 15;
    uint4 v = ((const uint4*)hbf)[(size_t)(base + node) * 16 + c16];
    *(uint4*)((char*)sX + node * 256 + ((c16 ^ (node & 7)) << 4)) = v;
  }
  __syncthreads();

  const int w = tid >> 6, l = tid & 63;
  facc acc[2][2];
#pragma unroll
  for (int i = 0; i < 2; i++)
#pragma unroll
    for (int j = 0; j < 2; j++) acc[i][j] = (facc)(0.f);

#pragma unroll
  for (int kt = 0; kt < 4; kt++) {
    bfrag A[2];
#pragma unroll
    for (int rt = 0; rt < 2; rt++) {
      int row = rt * 16 + (l & 15);
      int slot = kt * 4 + (l >> 4);
      A[rt] = *(const bfrag*)((const char*)sX + row * 256 + ((slot ^ (row & 7)) << 4));
    }
    const bfrag* gb = (const bfrag*)PB + (size_t)(kt * 8 + w * 2) * 64 + l;
#pragma unroll
    for (int ct = 0; ct < 2; ct++) {
      bfrag B = gb[ct * 64];
#pragma unroll
      for (int rt = 0; rt < 2; rt++)
        acc[rt][ct] = __builtin_amdgcn_mfma_f32_16x16x32_bf16(A[rt], B, acc[rt][ct], 0, 0, 0);
    }
  }

#pragma unroll
  for (int ct = 0; ct < 2; ct++) {
    int col = w * 32 + ct * 16 + (l & 15);
    float bb = b[col];
#pragma unroll
    for (int rt = 0; rt < 2; rt++)
#pragma unroll
      for (int j = 0; j < 4; j++) {
        int node = base + rt * 16 + ((l >> 4) << 2) + j;
        mbf[(size_t)node * 128 + col] = f2bf(acc[rt][ct][j] + bb);
      }
  }
}

// ---------------------------------------------------------------------------
// GRU via MFMA. X = [a_bf | h_bf] (K=256). Block: 256 thr = 4 waves, 32 nodes.
// Wave w owns channels w*32..w*32+31 for all gates:
//   packed col-tiles w*8+{0,1}=r, {2,3}=z, {4,5}=i_n (k<128), {6,7}=h_n (k>=128)
__global__ __launch_bounds__(256) void gru_mfma_kernel(const u16* __restrict__ abf,
                                                       u16* __restrict__ hbf,
                                                       float* __restrict__ h,
                                                       const u16* __restrict__ GB,
                                                       const float* __restrict__ b_ih,
                                                       const float* __restrict__ b_hh, int n) {
  __shared__ __align__(16) u16 sX[32 * 256];  // 16KB, XOR-swizzled
  const int tid = threadIdx.x;
  const int base = blockIdx.x * 32;
  // stage: 1024 x 16B chunks (cols 0..15 = a, 16..31 = h)
  for (int it = 0; it < 4; it++) {
    int cid = tid + 256 * it;
    int node = cid >> 5, c16 = cid & 31;
    uint4 v;
    if (c16 < 16) v = ((const uint4*)abf)[(size_t)(base + node) * 16 + c16];
    else v = ((const uint4*)hbf)[(size_t)(base + node) * 16 + (c16 - 16)];
    *(uint4*)((char*)sX + node * 512 + ((c16 ^ (node & 7)) << 4)) = v;
  }
  __syncthreads();

  const int w = tid >> 6, l = tid & 63;
  facc accR[2][2], accZ[2][2], accIN[2][2], accHN[2][2];
#pragma unroll
  for (int i = 0; i < 2; i++)
#pragma unroll
    for (int j = 0; j < 2; j++) {
      accR[i][j] = (facc)(0.f); accZ[i][j] = (facc)(0.f);
      accIN[i][j] = (facc)(0.f); accHN[i][j] = (facc)(0.f);
    }

#pragma unroll
  for (int kt = 0; kt < 8; kt++) {
    bfrag A[2];
#pragma unroll
    for (int rt = 0; rt < 2; rt++) {
      int row = rt * 16 + (l & 15);
      int slot = kt * 4 + (l >> 4);
      A[rt] = *(const bfrag*)((const char*)sX + row * 512 + ((slot ^ (row & 7)) << 4));
    }
    const bfrag* gb = (const bfrag*)GB + (size_t)(kt * 32 + w * 8) * 64 + l;
#pragma unroll
    for (int s2 = 0; s2 < 2; s2++) {
      bfrag Br = gb[s2 * 64];
      bfrag Bz = gb[(2 + s2) * 64];
#pragma unroll
      for (int rt = 0; rt < 2; rt++) {
        accR[rt][s2] = __builtin_amdgcn_mfma_f32_16x16x32_bf16(A[rt], Br, accR[rt][s2], 0, 0, 0);
        accZ[rt][s2] = __builtin_amdgcn_mfma_f32_16x16x32_bf16(A[rt], Bz, accZ[rt][s2], 0, 0, 0);
      }
    }
    if (kt < 4) {
#pragma unroll
      for (int s2 = 0; s2 < 2; s2++) {
        bfrag Bi = gb[(4 + s2) * 64];
#pragma unroll
        for (int rt = 0; rt < 2; rt++)
          accIN[rt][s2] = __builtin_amdgcn_mfma_f32_16x16x32_bf16(A[rt], Bi, accIN[rt][s2], 0, 0, 0);
      }
    } else {
#pragma unroll
      for (int s2 = 0; s2 < 2; s2++) {
        bfrag Bh = gb[(6 + s2) * 64];
#pragma unroll
        for (int rt = 0; rt < 2; rt++)
          accHN[rt][s2] = __builtin_amdgcn_mfma_f32_16x16x32_bf16(A[rt], Bh, accHN[rt][s2], 0, 0, 0);
      }
    }
  }

#pragma unroll
  for (int s2 = 0; s2 < 2; s2++) {
    int ch = w * 32 + s2 * 16 + (l & 15);
    float biR = b_ih[ch], bhR = b_hh[ch];
    float biZ = b_ih[128 + ch], bhZ = b_hh[128 + ch];
    float biN = b_ih[256 + ch], bhN = b_hh[256 + ch];
#pragma unroll
    for (int rt = 0; rt < 2; rt++)
#pragma unroll
      for (int j = 0; j < 4; j++) {
        int g = base + rt * 16 + ((l >> 4) << 2) + j;
        float r = sigf(accR[rt][s2][j] + biR + bhR);
        float z = sigf(accZ[rt][s2][j] + biZ + bhZ);
        float nn = tanh_fast(accIN[rt][s2][j] + biN + r * (accHN[rt][s2][j] + bhN));
        float ho = h[(size_t)g * 128 + ch];
        float hnew = (1.f - z) * nn + z * ho;
        h[(size_t)g * 128 + ch] = hnew;
        hbf[(size_t)g * 128 + ch] = f2bf(hnew);
      }
  }
}

// ---------------------------------------------------------------------------
__global__ __launch_bounds__(256) void head_kernel(const float* __restrict__ h,
                                                   const float* __restrict__ fc_w,
                                                   const float* __restrict__ fc_b,
                                                   float* __restrict__ out, int n) {
  int wave = (blockIdx.x * 256 + threadIdx.x) >> 6;
  int lane = threadIdx.x & 63;
  if (wave >= n) return;
  float2 hv = ((const float2*)h)[(size_t)wave * 64 + lane];
  float2 w0 = ((const float2*)fc_w)[lane];
  float2 w1 = ((const float2*)fc_w)[64 + lane];
  float p0 = hv.x * w0.x + hv.y * w0.y;
  float p1 = hv.x * w1.x + hv.y * w1.y;
#pragma unroll
  for (int off = 32; off > 0; off >>= 1) {
    p0 += __shfl_down(p0, off, 64);
    p1 += __shfl_down(p1, off, 64);
  }
  if (lane == 0) {
    out[(size_t)wave * 2 + 0] = p0 + fc_b[0];
    out[(size_t)wave * 2 + 1] = p1 + fc_b[1];
  }
}

// ---------------------------------------------------------------------------
extern "C" void kernel_launch(void* const* d_in, const int* in_sizes, int n_in,
                              void* d_out, int out_size, void* d_ws, size_t ws_size,
                              hipStream_t stream) {
  const float* feat = (const float*)d_in[0];
  const int* src = (const int*)d_in[1];
  const int* dst = (const int*)d_in[2];
  const int N = in_sizes[0] / 64;
  const int E = in_sizes[1];

  const float* Wl[2]  = {(const float*)d_in[3], (const float*)d_in[9]};
  const float* bl[2]  = {(const float*)d_in[4], (const float*)d_in[10]};
  const float* wih[2] = {(const float*)d_in[5], (const float*)d_in[11]};
  const float* whh[2] = {(const float*)d_in[6], (const float*)d_in[12]};
  const float* bih[2] = {(const float*)d_in[7], (const float*)d_in[13]};
  const float* bhh[2] = {(const float*)d_in[8], (const float*)d_in[14]};
  const float* fcw = (const float*)d_in[15];
  const float* fcb = (const float*)d_in[16];

  // workspace layout (16B-aligned by construction)
  float* h = (float*)d_ws;                       // N*128 f32
  u16* hbf = (u16*)(h + (size_t)N * 128);        // N*128 bf16
  u16* mbf = hbf + (size_t)N * 128;
  u16* abf = mbf + (size_t)N * 128;
  u16* PB[2]; PB[0] = abf + (size_t)N * 128; PB[1] = PB[0] + 16384;
  u16* GB[2]; GB[0] = PB[1] + 16384; GB[1] = GB[0] + 131072;
  int* rowptr = (int*)(GB[1] + 131072);          // N+1
  int* deg = rowptr + (N + 1);
  int* csr_src = deg + N;
  int* bsums = csr_src + E;

  // --- one-time: weight packing + pad + CSR build ---
  for (int l = 0; l < 2; l++) {
    pack_lin_kernel<<<64, 256, 0, stream>>>(Wl[l], PB[l]);
    pack_gru_kernel<<<512, 256, 0, stream>>>(wih[l], whh[l], GB[l]);
  }
  pad2_kernel<<<(N * 32 + 255) / 256, 256, 0, stream>>>(feat, h, hbf, N);

  int nb = (N + 4095) / 4096;
  hipMemsetAsync(deg, 0, (size_t)N * sizeof(int), stream);
  hist_kernel<<<(E + 255) / 256, 256, 0, stream>>>(dst, deg, E);
  scan1_kernel<<<nb, 256, 0, stream>>>(deg, rowptr, bsums, N);
  scan_tops_kernel<<<1, 256, 0, stream>>>(bsums, nb);
  scan_add_kernel<<<(N + 256) / 256, 256, 0, stream>>>(rowptr, bsums, N, E);
  hipMemsetAsync(deg, 0, (size_t)N * sizeof(int), stream);
  bucket_kernel<<<(E + 255) / 256, 256, 0, stream>>>(src, dst, rowptr, deg, csr_src, E);

  // --- main loop ---
  int nblk = (N + 31) / 32;
  for (int layer = 0; layer < 2; layer++) {
    for (int step = 0; step < 5; step++) {
      lin_mfma_kernel<<<nblk, 256, 0, stream>>>(hbf, PB[layer], bl[layer], mbf, N);
      gather_kernel<<<(N + 7) / 8, 256, 0, stream>>>(mbf, rowptr, csr_src, abf, N);
      gru_mfma_kernel<<<nblk, 256, 0, stream>>>(abf, hbf, h, GB[layer], bih[layer], bhh[layer], N);
    }
  }

  head_kernel<<<(N + 3) / 4, 256, 0, stream>>>(h, fcw, fcb, (float*)d_out, N);
}

// Round 6
// 1234.790 us; speedup vs baseline: 19.4223x; 1.1975x over previous
//
#include <hip/hip_runtime.h>

#define N_HID 128
typedef unsigned short u16;
typedef unsigned int u32;
typedef __attribute__((ext_vector_type(8))) short bfrag;   // 8 bf16 = 4 VGPR
typedef __attribute__((ext_vector_type(4))) float facc;    // 4 f32 acc

__device__ __forceinline__ float sigf(float x) { return 1.f / (1.f + __expf(-x)); }
__device__ __forceinline__ float tanh_fast(float x) { return 1.f - 2.f / (__expf(2.f * x) + 1.f); }
__device__ __forceinline__ u16 f2bf(float f) {
  u32 u = __float_as_uint(f);
  u += 0x7fffu + ((u >> 16) & 1u);
  return (u16)(u >> 16);
}
__device__ __forceinline__ float bf2f(u16 b) { return __uint_as_float(((u32)b) << 16); }

// ---------------------------------------------------------------------------
// WIH2[gc][k] = sum_c wih[gc][c] * W[c][k]   (fold edge-linear into GRU input weights)
__global__ __launch_bounds__(256) void wihw_kernel(const float* __restrict__ wih,
                                                   const float* __restrict__ W,
                                                   float* __restrict__ out) {
  int i = blockIdx.x * 256 + threadIdx.x;  // 384*128 = 49152
  if (i >= 49152) return;
  int gc = i >> 7, k = i & 127;
  float acc = 0.f;
  for (int c = 0; c < 128; c++) acc = fmaf(wih[gc * 128 + c], W[c * 128 + k], acc);
  out[i] = acc;
}

// wb[gc] = sum_c wih[gc][c] * b[c]  (deg-scaled bias term)
__global__ __launch_bounds__(256) void wb_kernel(const float* __restrict__ wih,
                                                 const float* __restrict__ b,
                                                 float* __restrict__ wb) {
  int gc = blockIdx.x * 256 + threadIdx.x;
  if (gc >= 384) return;
  float acc = 0.f;
  for (int c = 0; c < 128; c++) acc = fmaf(wih[gc * 128 + c], b[c], acc);
  wb[gc] = acc;
}

// pack GRU weights. Packed col-tiles pct 0..31: cw=pct>>3, t=pct&7,
// kind=t>>1 (0=r,1=z,2=i_n,3=h_n), sub=t&1, ch=cw*32+sub*16+(l&15).
// K axis = [s(0..127) | h(128..255)], k = kt*32+(l>>4)*8+e.
__global__ __launch_bounds__(256) void pack_gru_kernel(const float* __restrict__ wih,
                                                       const float* __restrict__ whh,
                                                       u16* __restrict__ GB) {
  int i = blockIdx.x * 256 + threadIdx.x;  // 8*32*64*8 = 131072
  if (i >= 131072) return;
  int e = i & 7, l = (i >> 3) & 63, pct = (i >> 9) & 31, kt = i >> 14;
  int cw = pct >> 3, t = pct & 7, kind = t >> 1, sub = t & 1;
  int ch = cw * 32 + sub * 16 + (l & 15);
  int k = kt * 32 + ((l >> 4) << 3) + e;
  float v = 0.f;
  if (kind == 0) v = (k < 128) ? wih[ch * 128 + k] : whh[ch * 128 + k - 128];
  else if (kind == 1) v = (k < 128) ? wih[(128 + ch) * 128 + k] : whh[(128 + ch) * 128 + k - 128];
  else if (kind == 2) v = (k < 128) ? wih[(256 + ch) * 128 + k] : 0.f;
  else v = (k >= 128) ? whh[(256 + ch) * 128 + k - 128] : 0.f;
  GB[i] = f2bf(v);
}

// ---------------------------------------------------------------------------
// pad features [n,64] -> h f32 [n,128] and hbf bf16 [n,128]
__global__ __launch_bounds__(256) void pad2_kernel(const float* __restrict__ feat,
                                                   float* __restrict__ h,
                                                   u16* __restrict__ hbf, int n) {
  int i = blockIdx.x * 256 + threadIdx.x;
  if (i >= n * 32) return;
  int node = i >> 5, c4 = i & 31;
  float4 v = make_float4(0.f, 0.f, 0.f, 0.f);
  if (c4 < 16) v = ((const float4*)feat)[(size_t)node * 16 + c4];
  ((float4*)h)[i] = v;
  u32 p0 = (u32)f2bf(v.x) | ((u32)f2bf(v.y) << 16);
  u32 p1 = (u32)f2bf(v.z) | ((u32)f2bf(v.w) << 16);
  ((uint2*)hbf)[i] = make_uint2(p0, p1);
}

// ---------------------------------------------------------------------------
// CSR build
__global__ __launch_bounds__(256) void hist_kernel(const int* __restrict__ dst,
                                                   int* __restrict__ deg, int E) {
  int e = blockIdx.x * 256 + threadIdx.x;
  if (e < E) atomicAdd(&deg[dst[e]], 1);
}

__global__ __launch_bounds__(256) void scan1_kernel(const int* __restrict__ deg,
                                                    int* __restrict__ out,
                                                    int* __restrict__ bsums, int n) {
  __shared__ int s[256];
  int t = threadIdx.x;
  int base = blockIdx.x * 4096 + t * 16;
  int v[16];
  int local = 0;
#pragma unroll
  for (int i = 0; i < 16; i++) {
    int x = (base + i < n) ? deg[base + i] : 0;
    v[i] = local;
    local += x;
  }
  s[t] = local;
  __syncthreads();
  for (int off = 1; off < 256; off <<= 1) {
    int add = (t >= off) ? s[t - off] : 0;
    __syncthreads();
    s[t] += add;
    __syncthreads();
  }
  int texcl = s[t] - local;
#pragma unroll
  for (int i = 0; i < 16; i++)
    if (base + i < n) out[base + i] = texcl + v[i];
  if (t == 255) bsums[blockIdx.x] = s[255];
}

__global__ __launch_bounds__(256) void scan_tops_kernel(int* __restrict__ bsums, int nb) {
  __shared__ int s[256];
  int t = threadIdx.x;
  int orig = (t < nb) ? bsums[t] : 0;
  s[t] = orig;
  __syncthreads();
  for (int off = 1; off < 256; off <<= 1) {
    int add = (t >= off) ? s[t - off] : 0;
    __syncthreads();
    s[t] += add;
    __syncthreads();
  }
  if (t < nb) bsums[t] = s[t] - orig;
}

__global__ __launch_bounds__(256) void scan_add_kernel(int* __restrict__ rowptr,
                                                       const int* __restrict__ bsums,
                                                       int n, int E) {
  int i = blockIdx.x * 256 + threadIdx.x;
  if (i < n) rowptr[i] += bsums[i / 4096];
  if (i == n) rowptr[n] = E;
}

__global__ __launch_bounds__(256) void bucket_kernel(const int* __restrict__ src,
                                                     const int* __restrict__ dst,
                                                     const int* __restrict__ rowptr,
                                                     int* __restrict__ cursor,
                                                     int* __restrict__ csr_src, int E) {
  int e = blockIdx.x * 256 + threadIdx.x;
  if (e >= E) return;
  int d = dst[e];
  int p = atomicAdd(&cursor[d], 1);
  csr_src[rowptr[d] + p] = src[e];
}
// NOTE: after bucket_kernel, cursor[] == degree[] again — reused as deg input to gru.

// ---------------------------------------------------------------------------
// sbf[d] = bf16( sum_{incoming} f32(hbf[src]) ); 32 lanes x 4 channels per node
__global__ __launch_bounds__(256) void gather_kernel(const u16* __restrict__ hbf,
                                                     const int* __restrict__ rowptr,
                                                     const int* __restrict__ csr_src,
                                                     u16* __restrict__ sbf, int n) {
  int tid = threadIdx.x;
  int node = blockIdx.x * 8 + (tid >> 5);
  if (node >= n) return;
  int c = tid & 31;  // 4 bf16 channels
  int beg = rowptr[node], end = rowptr[node + 1];
  float a0 = 0.f, a1 = 0.f, a2 = 0.f, a3 = 0.f;
  for (int j = beg; j < end; j++) {
    int s = csr_src[j];
    uint2 mv = ((const uint2*)hbf)[(size_t)s * 32 + c];
    a0 += bf2f((u16)(mv.x & 0xffff));
    a1 += bf2f((u16)(mv.x >> 16));
    a2 += bf2f((u16)(mv.y & 0xffff));
    a3 += bf2f((u16)(mv.y >> 16));
  }
  u32 p0 = (u32)f2bf(a0) | ((u32)f2bf(a1) << 16);
  u32 p1 = (u32)f2bf(a2) | ((u32)f2bf(a3) << 16);
  ((uint2*)sbf)[(size_t)node * 32 + c] = make_uint2(p0, p1);
}

// ---------------------------------------------------------------------------
// Fused GRU via MFMA. X = [s_bf | h_bf] (K=256). Block: 512 thr = 8 waves, 64 nodes.
// Wave w: cw=w&3 -> channels cw*32..cw*32+31 (all gates); nh=w>>2 -> nodes nh*32..+31.
// Input-gate weights are WIH2 = w_ih@W (folded edge-linear); per-node bias deg*wb.
__global__ __launch_bounds__(512) void gru_mfma_kernel(const u16* __restrict__ sbf,
                                                       u16* __restrict__ hbf,
                                                       float* __restrict__ h,
                                                       const u16* __restrict__ GB,
                                                       const float* __restrict__ b_ih,
                                                       const float* __restrict__ b_hh,
                                                       const float* __restrict__ wb,
                                                       const int* __restrict__ deg, int n) {
  __shared__ __align__(16) u16 sX[64 * 256];  // 32 KB, XOR-swizzled
  const int tid = threadIdx.x;
  const int base = blockIdx.x * 64;
  // stage: 2048 x 16B chunks (chunk 0..15 = s, 16..31 = h per node)
  for (int it = 0; it < 4; it++) {
    int cid = it * 512 + tid;
    int node = cid >> 5, c = cid & 31;
    int gn = base + node;
    if (gn >= n) gn = n - 1;
    uint4 v = (c < 16) ? ((const uint4*)sbf)[(size_t)gn * 16 + c]
                       : ((const uint4*)hbf)[(size_t)gn * 16 + (c - 16)];
    *(uint4*)((char*)sX + node * 512 + ((c ^ (node & 7)) << 4)) = v;
  }
  __syncthreads();

  const int w = tid >> 6, l = tid & 63;
  const int cw = w & 3, nh = w >> 2;
  facc accR[2][2], accZ[2][2], accIN[2][2], accHN[2][2];
#pragma unroll
  for (int i = 0; i < 2; i++)
#pragma unroll
    for (int j = 0; j < 2; j++) {
      accR[i][j] = (facc)(0.f); accZ[i][j] = (facc)(0.f);
      accIN[i][j] = (facc)(0.f); accHN[i][j] = (facc)(0.f);
    }

#pragma unroll
  for (int kt = 0; kt < 8; kt++) {
    bfrag A[2];
#pragma unroll
    for (int rt = 0; rt < 2; rt++) {
      int row = nh * 32 + rt * 16 + (l & 15);
      int slot = kt * 4 + (l >> 4);
      A[rt] = *(const bfrag*)((const char*)sX + row * 512 + ((slot ^ (row & 7)) << 4));
    }
    const bfrag* gb = (const bfrag*)GB + (size_t)(kt * 32 + cw * 8) * 64 + l;
#pragma unroll
    for (int s2 = 0; s2 < 2; s2++) {
      bfrag Br = gb[s2 * 64];
      bfrag Bz = gb[(2 + s2) * 64];
#pragma unroll
      for (int rt = 0; rt < 2; rt++) {
        accR[rt][s2] = __builtin_amdgcn_mfma_f32_16x16x32_bf16(A[rt], Br, accR[rt][s2], 0, 0, 0);
        accZ[rt][s2] = __builtin_amdgcn_mfma_f32_16x16x32_bf16(A[rt], Bz, accZ[rt][s2], 0, 0, 0);
      }
    }
    if (kt < 4) {
#pragma unroll
      for (int s2 = 0; s2 < 2; s2++) {
        bfrag Bi = gb[(4 + s2) * 64];
#pragma unroll
        for (int rt = 0; rt < 2; rt++)
          accIN[rt][s2] = __builtin_amdgcn_mfma_f32_16x16x32_bf16(A[rt], Bi, accIN[rt][s2], 0, 0, 0);
      }
    } else {
#pragma unroll
      for (int s2 = 0; s2 < 2; s2++) {
        bfrag Bh = gb[(6 + s2) * 64];
#pragma unroll
        for (int rt = 0; rt < 2; rt++)
          accHN[rt][s2] = __builtin_amdgcn_mfma_f32_16x16x32_bf16(A[rt], Bh, accHN[rt][s2], 0, 0, 0);
      }
    }
  }

#pragma unroll
  for (int s2 = 0; s2 < 2; s2++) {
    int ch = cw * 32 + s2 * 16 + (l & 15);
    float biR = b_ih[ch], bhR = b_hh[ch], wbR = wb[ch];
    float biZ = b_ih[128 + ch], bhZ = b_hh[128 + ch], wbZ = wb[128 + ch];
    float biN = b_ih[256 + ch], bhN = b_hh[256 + ch], wbN = wb[256 + ch];
#pragma unroll
    for (int rt = 0; rt < 2; rt++)
#pragma unroll
      for (int j = 0; j < 4; j++) {
        int g = base + nh * 32 + rt * 16 + ((l >> 4) << 2) + j;
        if (g < n) {
          float dg = (float)deg[g];
          float r = sigf(accR[rt][s2][j] + biR + dg * wbR + bhR);
          float z = sigf(accZ[rt][s2][j] + biZ + dg * wbZ + bhZ);
          float nn = tanh_fast(accIN[rt][s2][j] + biN + dg * wbN + r * (accHN[rt][s2][j] + bhN));
          float ho = h[(size_t)g * 128 + ch];
          float hnew = (1.f - z) * nn + z * ho;
          h[(size_t)g * 128 + ch] = hnew;
          hbf[(size_t)g * 128 + ch] = f2bf(hnew);
        }
      }
  }
}

// ---------------------------------------------------------------------------
__global__ __launch_bounds__(256) void head_kernel(const float* __restrict__ h,
                                                   const float* __restrict__ fc_w,
                                                   const float* __restrict__ fc_b,
                                                   float* __restrict__ out, int n) {
  int wave = (blockIdx.x * 256 + threadIdx.x) >> 6;
  int lane = threadIdx.x & 63;
  if (wave >= n) return;
  float2 hv = ((const float2*)h)[(size_t)wave * 64 + lane];
  float2 w0 = ((const float2*)fc_w)[lane];
  float2 w1 = ((const float2*)fc_w)[64 + lane];
  float p0 = hv.x * w0.x + hv.y * w0.y;
  float p1 = hv.x * w1.x + hv.y * w1.y;
#pragma unroll
  for (int off = 32; off > 0; off >>= 1) {
    p0 += __shfl_down(p0, off, 64);
    p1 += __shfl_down(p1, off, 64);
  }
  if (lane == 0) {
    out[(size_t)wave * 2 + 0] = p0 + fc_b[0];
    out[(size_t)wave * 2 + 1] = p1 + fc_b[1];
  }
}

// ---------------------------------------------------------------------------
extern "C" void kernel_launch(void* const* d_in, const int* in_sizes, int n_in,
                              void* d_out, int out_size, void* d_ws, size_t ws_size,
                              hipStream_t stream) {
  const float* feat = (const float*)d_in[0];
  const int* src = (const int*)d_in[1];
  const int* dst = (const int*)d_in[2];
  const int N = in_sizes[0] / 64;
  const int E = in_sizes[1];

  const float* Wl[2]  = {(const float*)d_in[3], (const float*)d_in[9]};
  const float* bl[2]  = {(const float*)d_in[4], (const float*)d_in[10]};
  const float* wih[2] = {(const float*)d_in[5], (const float*)d_in[11]};
  const float* whh[2] = {(const float*)d_in[6], (const float*)d_in[12]};
  const float* bih[2] = {(const float*)d_in[7], (const float*)d_in[13]};
  const float* bhh[2] = {(const float*)d_in[8], (const float*)d_in[14]};
  const float* fcw = (const float*)d_in[15];
  const float* fcb = (const float*)d_in[16];

  // workspace layout (16B-aligned by construction)
  float* h = (float*)d_ws;                       // N*128 f32
  u16* hbf = (u16*)(h + (size_t)N * 128);        // N*128 bf16
  u16* sbf = hbf + (size_t)N * 128;              // N*128 bf16
  float* WIH2[2];
  WIH2[0] = (float*)(sbf + (size_t)N * 128);
  WIH2[1] = WIH2[0] + 49152;
  float* wb2[2] = {WIH2[1] + 49152, WIH2[1] + 49152 + 384};
  u16* GB[2];
  GB[0] = (u16*)(wb2[1] + 384);
  GB[1] = GB[0] + 131072;
  int* rowptr = (int*)(GB[1] + 131072);          // N+1
  int* deg = rowptr + (N + 1);                   // cursor during bucket; ends as degree
  int* csr_src = deg + N;
  int* bsums = csr_src + E;

  // --- one-time: weight fold+pack + pad + CSR build ---
  for (int l = 0; l < 2; l++) {
    wihw_kernel<<<192, 256, 0, stream>>>(wih[l], Wl[l], WIH2[l]);
    wb_kernel<<<2, 256, 0, stream>>>(wih[l], bl[l], wb2[l]);
    pack_gru_kernel<<<512, 256, 0, stream>>>(WIH2[l], whh[l], GB[l]);
  }
  pad2_kernel<<<(N * 32 + 255) / 256, 256, 0, stream>>>(feat, h, hbf, N);

  int nb = (N + 4095) / 4096;
  hipMemsetAsync(deg, 0, (size_t)N * sizeof(int), stream);
  hist_kernel<<<(E + 255) / 256, 256, 0, stream>>>(dst, deg, E);
  scan1_kernel<<<nb, 256, 0, stream>>>(deg, rowptr, bsums, N);
  scan_tops_kernel<<<1, 256, 0, stream>>>(bsums, nb);
  scan_add_kernel<<<(N + 256) / 256, 256, 0, stream>>>(rowptr, bsums, N, E);
  hipMemsetAsync(deg, 0, (size_t)N * sizeof(int), stream);
  bucket_kernel<<<(E + 255) / 256, 256, 0, stream>>>(src, dst, rowptr, deg, csr_src, E);

  // --- main loop: per step just gather + fused GRU ---
  int nblk = (N + 63) / 64;
  for (int layer = 0; layer < 2; layer++) {
    for (int step = 0; step < 5; step++) {
      gather_kernel<<<(N + 7) / 8, 256, 0, stream>>>(hbf, rowptr, csr_src, sbf, N);
      gru_mfma_kernel<<<nblk, 512, 0, stream>>>(sbf, hbf, h, GB[layer], bih[layer], bhh[layer],
                                                wb2[layer], deg, N);
    }
  }

  head_kernel<<<(N + 3) / 4, 256, 0, stream>>>(h, fcw, fcb, (float*)d_out, N);
}